// Round 2
// baseline (136.038 us; speedup 1.0000x reference)
//
#include <hip/hip_runtime.h>

#define DD 128
#define BM 64
#define CHUNK 2          // tiles per block -> 128 contiguous rows/block, grid 1024
#define T_TYPES 16

typedef __bf16 bf16x8 __attribute__((ext_vector_type(8)));
typedef __bf16 bf16x4 __attribute__((ext_vector_type(4)));
typedef float  f32x4  __attribute__((ext_vector_type(4)));

// async 16B global->LDS DMA: per-lane global addr, wave-uniform LDS base,
// HW scatters lane i at base + i*16.
__device__ __forceinline__ void async_copy16(const void* g, void* l) {
    __builtin_amdgcn_global_load_lds(
        (const __attribute__((address_space(1))) unsigned int*)g,
        (__attribute__((address_space(3))) unsigned int*)l, 16, 0, 0);
}

// ---------- Pre-kernel: w fp32 [t][k][n] -> bf16 MFMA-fragment order ----------
// wbf layout: [t][nt(8)][kk(4)][lane(64)][j(8)] bf16; B-fragment for (nt,kk)
// held by lane(q,n16) is B[k=kk*32+q*8+j][n=nt*16+n16] = w[t][k][n].
__global__ __launch_bounds__(256) void transpose_w_frag_kernel(
    const float* __restrict__ w, unsigned short* __restrict__ wbf)
{
    __shared__ float lds[DD * 33];
    const int t   = blockIdx.x >> 2;
    const int n0  = (blockIdx.x & 3) * 32;
    const int tid = threadIdx.x;
    const float* wt = w + (size_t)t * DD * DD;

    #pragma unroll
    for (int i = 0; i < 4; ++i) {
        int f = tid + i * 256;
        int k = f >> 3;
        int c = (f & 7) * 4;
        float4 v = *(const float4*)&wt[k * DD + n0 + c];
        lds[k * 33 + c + 0] = v.x;
        lds[k * 33 + c + 1] = v.y;
        lds[k * 33 + c + 2] = v.z;
        lds[k * 33 + c + 3] = v.w;
    }
    __syncthreads();
    #pragma unroll
    for (int i = 0; i < 4; ++i) {
        int g  = tid + i * 256;
        int nl = g >> 5;
        int k4 = (g & 31) * 4;
        int n  = n0 + nl;
        int nt  = n >> 4, n16 = n & 15;
        int kk  = k4 >> 5, q = (k4 >> 3) & 3, jb = k4 & 7;
        int lane = q * 16 + n16;
        size_t ofs = ((((size_t)t * 8 + nt) * 4 + kk) * 64 + lane) * 8 + jb;
        ushort4 o;
        union { __bf16 b; unsigned short u; } cv;
        cv.b = (__bf16)lds[(k4 + 0) * 33 + nl]; o.x = cv.u;
        cv.b = (__bf16)lds[(k4 + 1) * 33 + nl]; o.y = cv.u;
        cv.b = (__bf16)lds[(k4 + 2) * 33 + nl]; o.z = cv.u;
        cv.b = (__bf16)lds[(k4 + 3) * 33 + nl]; o.w = cv.u;
        *(ushort4*)&wbf[ofs] = o;
    }
}

// ---------- Main kernel: 2-tile blocks, pipelined, barrier-free A path ----------
// LDS 48 KB -> 3 blocks/CU; launch_bounds(256,3) = 3 waves/EU = 12 waves/CU.
__global__ __launch_bounds__(256, 3) void hetero_main_kernel(
    const float* __restrict__ x,
    const int*   __restrict__ tv,
    const __bf16* __restrict__ wbf,   // fragment-ordered bf16 W
    const float* __restrict__ bias,   // [T][128]
    float*       __restrict__ out)    // [N][128]
{
    __shared__ __bf16 As[4 * 16 * DD];   // 4 per-wave private quadrants (16 KB)
    __shared__ __bf16 Bs[DD * DD];       // 32 KB, fragment order

    const int tid  = threadIdx.x;
    const int wave = tid >> 6;
    const int lane = tid & 63;
    const int q    = lane >> 4;
    const int n16  = lane & 15;
    const int chunk0 = blockIdx.x * (BM * CHUNK);

    __bf16* Aq = &As[wave * 16 * DD];

    int t_res = tv[chunk0];

    // ---- W[t_res] -> Bs: 8 async DMA insts/wave, zero VGPR cost ----
    {
        const char* gsrc = (const char*)(wbf + (size_t)t_res * DD * DD);
        char* ldst = (char*)Bs;
        const int wofs = wave * 1024 + lane * 16;
        #pragma unroll
        for (int r = 0; r < 8; ++r)
            async_copy16(gsrc + r * 4096 + wofs, ldst + r * 4096 + wave * 1024);
    }

    // bias cached in regs for resident type
    float bv[8];
    #pragma unroll
    for (int nt = 0; nt < 8; ++nt) bv[nt] = bias[t_res * DD + nt * 16 + n16];

    // ---- prefetch x tile 0 (wave's own 16 rows, perfectly coalesced) ----
    f32x4 xf[8];
    {
        const f32x4* p = (const f32x4*)(x + (size_t)(chunk0 + wave * 16) * DD);
        #pragma unroll
        for (int j = 0; j < 8; ++j) xf[j] = __builtin_nontemporal_load(&p[lane + 64 * j]);
    }

    __syncthreads();   // drain W DMA (all waves read all of Bs)

    #pragma unroll
    for (int tile = 0; tile < CHUNK; ++tile) {
        const int trow0 = chunk0 + tile * BM;
        const int wrow0 = trow0 + wave * 16;

        // issue next tile's prefetch first -> loads fly under this tile's compute
        f32x4 xn[8];
        if (tile + 1 < CHUNK) {
            const f32x4* p = (const f32x4*)(x + (size_t)(wrow0 + BM) * DD);
            #pragma unroll
            for (int j = 0; j < 8; ++j) xn[j] = __builtin_nontemporal_load(&p[lane + 64 * j]);
        }

        // stage current tile into this wave's LDS quadrant (swizzled granules).
        // Same-wave DS ordering => no barrier needed anywhere on the A path.
        #pragma unroll
        for (int j = 0; j < 8; ++j) {
            int f  = lane + 64 * j;
            int r  = f >> 5;
            int c4 = (f & 31) << 2;
            int g  = c4 >> 3;
            bf16x4 pk;
            pk[0] = (__bf16)xf[j][0]; pk[1] = (__bf16)xf[j][1];
            pk[2] = (__bf16)xf[j][2]; pk[3] = (__bf16)xf[j][3];
            *(bf16x4*)&Aq[r * DD + (((g ^ (r & 7)) << 3) | (c4 & 7))] = pk;
        }

        // A fragments: A[m=n16][k=kk*32+q*8+j], swizzle-corrected
        bf16x8 a[4];
        #pragma unroll
        for (int kk = 0; kk < 4; ++kk) {
            int gr = ((kk << 2) | q) ^ (n16 & 7);
            a[kk] = *(const bf16x8*)&Aq[n16 * DD + (gr << 3)];
        }

        const int tlo = tv[trow0];
        const int thi = tv[trow0 + BM - 1];

        for (int t = tlo; t <= thi; ++t) {
            if (t != t_res) {               // rare: block-uniform branch
                __syncthreads();            // all waves done reading old Bs
                const char* gsrc = (const char*)(wbf + (size_t)t * DD * DD);
                char* ldst = (char*)Bs;
                const int wofs = wave * 1024 + lane * 16;
                #pragma unroll
                for (int r = 0; r < 8; ++r)
                    async_copy16(gsrc + r * 4096 + wofs, ldst + r * 4096 + wave * 1024);
                t_res = t;
                #pragma unroll
                for (int nt = 0; nt < 8; ++nt) bv[nt] = bias[t * DD + nt * 16 + n16];
                __syncthreads();
            }

            f32x4 acc[8];
            #pragma unroll
            for (int nt = 0; nt < 8; ++nt) acc[nt] = (f32x4){0.f, 0.f, 0.f, 0.f};

            #pragma unroll
            for (int nt = 0; nt < 8; ++nt) {
                #pragma unroll
                for (int kk = 0; kk < 4; ++kk) {
                    bf16x8 b = *(const bf16x8*)&Bs[(((nt << 2) | kk) << 9) | (lane << 3)];
                    acc[nt] = __builtin_amdgcn_mfma_f32_16x16x32_bf16(a[kk], b, acc[nt], 0, 0, 0);
                }
            }

            // epilogue: D[row=q*4+reg][col=nt*16+n16]; 4x64B segments per store
            const int rbase = wrow0 + q * 4;
            bool m0 = true, m1 = true, m2 = true, m3 = true;
            if (tlo != thi) {
                m0 = (tv[rbase + 0] == t);
                m1 = (tv[rbase + 1] == t);
                m2 = (tv[rbase + 2] == t);
                m3 = (tv[rbase + 3] == t);
            }
            float* o = out + (size_t)rbase * DD + n16;
            #pragma unroll
            for (int nt = 0; nt < 8; ++nt) {
                float* oc = o + nt * 16;
                if (m0) __builtin_nontemporal_store(acc[nt][0] + bv[nt], &oc[0 * DD]);
                if (m1) __builtin_nontemporal_store(acc[nt][1] + bv[nt], &oc[1 * DD]);
                if (m2) __builtin_nontemporal_store(acc[nt][2] + bv[nt], &oc[2 * DD]);
                if (m3) __builtin_nontemporal_store(acc[nt][3] + bv[nt], &oc[3 * DD]);
            }
        }

        // hand prefetch buffer over
        #pragma unroll
        for (int j = 0; j < 8; ++j) xf[j] = xn[j];
    }
}

extern "C" void kernel_launch(void* const* d_in, const int* in_sizes, int n_in,
                              void* d_out, int out_size, void* d_ws, size_t ws_size,
                              hipStream_t stream) {
    const float* x    = (const float*)d_in[0];
    const int*   tv   = (const int*)d_in[1];
    const float* w    = (const float*)d_in[2];
    const float* bias = (const float*)d_in[3];
    float*       out  = (float*)d_out;
    unsigned short* wbf = (unsigned short*)d_ws;   // 512 KB

    int nrows = in_sizes[0] / DD;                  // 131072
    int grid  = nrows / (BM * CHUNK);              // 1024

    hipLaunchKernelGGL(transpose_w_frag_kernel, dim3(T_TYPES * 4), dim3(256), 0, stream,
                       w, wbf);
    hipLaunchKernelGGL(hetero_main_kernel, dim3(grid), dim3(256), 0, stream,
                       x, tv, (const __bf16*)wbf, bias, out);
}

// Round 3
// 123.800 us; speedup vs baseline: 1.0989x; 1.0989x over previous
//
#include <hip/hip_runtime.h>

#define DD 128
#define BM 64
#define CHUNK 2          // tiles per block -> 128 contiguous rows/block, grid 1024
#define T_TYPES 16

typedef __bf16 bf16x8 __attribute__((ext_vector_type(8)));
typedef float  f32x4  __attribute__((ext_vector_type(4)));

// async 16B global->LDS DMA: per-lane global addr, wave-uniform LDS base,
// HW scatters lane i at base + i*16.
__device__ __forceinline__ void async_copy16(const void* g, void* l) {
    __builtin_amdgcn_global_load_lds(
        (const __attribute__((address_space(1))) unsigned int*)g,
        (__attribute__((address_space(3))) unsigned int*)l, 16, 0, 0);
}

// ---------- Pre-kernel: w fp32 [t][k][n] -> bf16 MFMA-fragment order ----------
// wbf layout: [t][nt(8)][kk(4)][lane(64)][j(8)] bf16; B-fragment for (nt,kk)
// held by lane(q,n16) is B[k=kk*32+q*8+j][n=nt*16+n16] = w[t][k][n].
__global__ __launch_bounds__(256) void transpose_w_frag_kernel(
    const float* __restrict__ w, unsigned short* __restrict__ wbf)
{
    __shared__ float lds[DD * 33];
    const int t   = blockIdx.x >> 2;
    const int n0  = (blockIdx.x & 3) * 32;
    const int tid = threadIdx.x;
    const float* wt = w + (size_t)t * DD * DD;

    #pragma unroll
    for (int i = 0; i < 4; ++i) {
        int f = tid + i * 256;
        int k = f >> 3;
        int c = (f & 7) * 4;
        float4 v = *(const float4*)&wt[k * DD + n0 + c];
        lds[k * 33 + c + 0] = v.x;
        lds[k * 33 + c + 1] = v.y;
        lds[k * 33 + c + 2] = v.z;
        lds[k * 33 + c + 3] = v.w;
    }
    __syncthreads();
    #pragma unroll
    for (int i = 0; i < 4; ++i) {
        int g  = tid + i * 256;
        int nl = g >> 5;
        int k4 = (g & 31) * 4;
        int n  = n0 + nl;
        int nt  = n >> 4, n16 = n & 15;
        int kk  = k4 >> 5, q = (k4 >> 3) & 3, jb = k4 & 7;
        int lane = q * 16 + n16;
        size_t ofs = ((((size_t)t * 8 + nt) * 4 + kk) * 64 + lane) * 8 + jb;
        ushort4 o;
        union { __bf16 b; unsigned short u; } cv;
        cv.b = (__bf16)lds[(k4 + 0) * 33 + nl]; o.x = cv.u;
        cv.b = (__bf16)lds[(k4 + 1) * 33 + nl]; o.y = cv.u;
        cv.b = (__bf16)lds[(k4 + 2) * 33 + nl]; o.z = cv.u;
        cv.b = (__bf16)lds[(k4 + 3) * 33 + nl]; o.w = cv.u;
        *(ushort4*)&wbf[ofs] = o;
    }
}

// ---------- Main kernel ----------
// A-fragments loaded DIRECTLY from global in MFMA layout (no LDS round-trip):
// lane(q,n16) needs A[m=n16][k=kk*32+q*8+j] = x[wrow0+n16][kk*32+q*8+j],
// i.e. two float4 loads per kk at 32B-aligned addresses. 128B/row segments.
// LDS holds only Bs (32 KB) -> 3 blocks/CU with launch_bounds(256,3).
__global__ __launch_bounds__(256, 3) void hetero_main_kernel(
    const float* __restrict__ x,
    const int*   __restrict__ tv,
    const __bf16* __restrict__ wbf,   // fragment-ordered bf16 W
    const float* __restrict__ bias,   // [T][128]
    float*       __restrict__ out)    // [N][128]
{
    __shared__ __bf16 Bs[DD * DD];       // 32 KB, fragment order

    const int tid  = threadIdx.x;
    const int wave = tid >> 6;
    const int lane = tid & 63;
    const int q    = lane >> 4;
    const int n16  = lane & 15;
    const int chunk0 = blockIdx.x * (BM * CHUNK);

    int t_res = tv[chunk0];

    // ---- W[t_res] -> Bs: 8 async DMA insts/wave, zero VGPR cost ----
    {
        const char* gsrc = (const char*)(wbf + (size_t)t_res * DD * DD);
        char* ldst = (char*)Bs;
        const int wofs = wave * 1024 + lane * 16;
        #pragma unroll
        for (int r = 0; r < 8; ++r)
            async_copy16(gsrc + r * 4096 + wofs, ldst + r * 4096 + wave * 1024);
    }

    // bias cached in regs for resident type
    float bv[8];
    #pragma unroll
    for (int nt = 0; nt < 8; ++nt) bv[nt] = bias[t_res * DD + nt * 16 + n16];

    // ---- prefetch x tile 0 directly in fragment order ----
    f32x4 xlo[4], xhi[4];
    {
        const float* base = x + (size_t)(chunk0 + wave * 16 + n16) * DD + q * 8;
        #pragma unroll
        for (int kk = 0; kk < 4; ++kk) {
            xlo[kk] = *(const f32x4*)(base + kk * 32);
            xhi[kk] = *(const f32x4*)(base + kk * 32 + 4);
        }
    }

    __syncthreads();   // drain W DMA (all waves read all of Bs)

    #pragma unroll
    for (int tile = 0; tile < CHUNK; ++tile) {
        const int trow0 = chunk0 + tile * BM;
        const int wrow0 = trow0 + wave * 16;

        // issue next tile's prefetch first -> loads fly under this tile's compute
        f32x4 nlo[4], nhi[4];
        if (tile + 1 < CHUNK) {
            const float* base = x + (size_t)(wrow0 + BM + n16) * DD + q * 8;
            #pragma unroll
            for (int kk = 0; kk < 4; ++kk) {
                nlo[kk] = *(const f32x4*)(base + kk * 32);
                nhi[kk] = *(const f32x4*)(base + kk * 32 + 4);
            }
        }

        // pack A fragments: A[m=n16][k=kk*32+q*8+j]
        bf16x8 a[4];
        #pragma unroll
        for (int kk = 0; kk < 4; ++kk) {
            bf16x8 t;
            t[0] = (__bf16)xlo[kk][0]; t[1] = (__bf16)xlo[kk][1];
            t[2] = (__bf16)xlo[kk][2]; t[3] = (__bf16)xlo[kk][3];
            t[4] = (__bf16)xhi[kk][0]; t[5] = (__bf16)xhi[kk][1];
            t[6] = (__bf16)xhi[kk][2]; t[7] = (__bf16)xhi[kk][3];
            a[kk] = t;
        }

        const int tlo = tv[trow0];
        const int thi = tv[trow0 + BM - 1];

        for (int t = tlo; t <= thi; ++t) {
            if (t != t_res) {               // rare: block-uniform branch
                __syncthreads();            // all waves done reading old Bs
                const char* gsrc = (const char*)(wbf + (size_t)t * DD * DD);
                char* ldst = (char*)Bs;
                const int wofs = wave * 1024 + lane * 16;
                #pragma unroll
                for (int r = 0; r < 8; ++r)
                    async_copy16(gsrc + r * 4096 + wofs, ldst + r * 4096 + wave * 1024);
                t_res = t;
                #pragma unroll
                for (int nt = 0; nt < 8; ++nt) bv[nt] = bias[t * DD + nt * 16 + n16];
                __syncthreads();
            }

            f32x4 acc[8];
            #pragma unroll
            for (int nt = 0; nt < 8; ++nt) acc[nt] = (f32x4){0.f, 0.f, 0.f, 0.f};

            #pragma unroll
            for (int nt = 0; nt < 8; ++nt) {
                #pragma unroll
                for (int kk = 0; kk < 4; ++kk) {
                    bf16x8 b = *(const bf16x8*)&Bs[(((nt << 2) | kk) << 9) | (lane << 3)];
                    acc[nt] = __builtin_amdgcn_mfma_f32_16x16x32_bf16(a[kk], b, acc[nt], 0, 0, 0);
                }
            }

            // epilogue: D[row=q*4+reg][col=nt*16+n16]; 4x64B segments per store,
            // adjacent nt pairs merge into full 128B lines in L2.
            const int rbase = wrow0 + q * 4;
            bool m0 = true, m1 = true, m2 = true, m3 = true;
            if (tlo != thi) {
                m0 = (tv[rbase + 0] == t);
                m1 = (tv[rbase + 1] == t);
                m2 = (tv[rbase + 2] == t);
                m3 = (tv[rbase + 3] == t);
            }
            float* o = out + (size_t)rbase * DD + n16;
            #pragma unroll
            for (int nt = 0; nt < 8; ++nt) {
                float* oc = o + nt * 16;
                if (m0) oc[0 * DD] = acc[nt][0] + bv[nt];
                if (m1) oc[1 * DD] = acc[nt][1] + bv[nt];
                if (m2) oc[2 * DD] = acc[nt][2] + bv[nt];
                if (m3) oc[3 * DD] = acc[nt][3] + bv[nt];
            }
        }

        // hand prefetch buffer over
        #pragma unroll
        for (int kk = 0; kk < 4; ++kk) { xlo[kk] = nlo[kk]; xhi[kk] = nhi[kk]; }
    }
}

extern "C" void kernel_launch(void* const* d_in, const int* in_sizes, int n_in,
                              void* d_out, int out_size, void* d_ws, size_t ws_size,
                              hipStream_t stream) {
    const float* x    = (const float*)d_in[0];
    const int*   tv   = (const int*)d_in[1];
    const float* w    = (const float*)d_in[2];
    const float* bias = (const float*)d_in[3];
    float*       out  = (float*)d_out;
    unsigned short* wbf = (unsigned short*)d_ws;   // 512 KB

    int nrows = in_sizes[0] / DD;                  // 131072
    int grid  = nrows / (BM * CHUNK);              // 1024

    hipLaunchKernelGGL(transpose_w_frag_kernel, dim3(T_TYPES * 4), dim3(256), 0, stream,
                       w, wbf);
    hipLaunchKernelGGL(hetero_main_kernel, dim3(grid), dim3(256), 0, stream,
                       x, tv, (const __bf16*)wbf, bias, out);
}

// Round 4
// 123.186 us; speedup vs baseline: 1.1043x; 1.0050x over previous
//
#include <hip/hip_runtime.h>

#define DD 128
#define BM 64
#define CHUNK 2          // tiles per block -> 128 contiguous rows/block, grid 1024
#define T_TYPES 16

typedef __bf16 bf16x8 __attribute__((ext_vector_type(8)));
typedef float  f32x4  __attribute__((ext_vector_type(4)));

// async 16B global->LDS DMA: per-lane global addr, wave-uniform LDS base,
// HW scatters lane i at base + i*16.
__device__ __forceinline__ void async_copy16(const void* g, void* l) {
    __builtin_amdgcn_global_load_lds(
        (const __attribute__((address_space(1))) unsigned int*)g,
        (__attribute__((address_space(3))) unsigned int*)l, 16, 0, 0);
}

// ---------- Pre-kernel: w fp32 [t][k][n] -> bf16 MFMA-fragment order ----------
// wbf layout: [t][nt(8)][kk(4)][lane(64)][j(8)] bf16; B-fragment for (nt,kk)
// held by lane(q,n16) is B[k=kk*32+q*8+j][n=nt*16+n16] = w[t][k][n].
__global__ __launch_bounds__(256) void transpose_w_frag_kernel(
    const float* __restrict__ w, unsigned short* __restrict__ wbf)
{
    __shared__ float lds[DD * 33];
    const int t   = blockIdx.x >> 2;
    const int n0  = (blockIdx.x & 3) * 32;
    const int tid = threadIdx.x;
    const float* wt = w + (size_t)t * DD * DD;

    #pragma unroll
    for (int i = 0; i < 4; ++i) {
        int f = tid + i * 256;
        int k = f >> 3;
        int c = (f & 7) * 4;
        float4 v = *(const float4*)&wt[k * DD + n0 + c];
        lds[k * 33 + c + 0] = v.x;
        lds[k * 33 + c + 1] = v.y;
        lds[k * 33 + c + 2] = v.z;
        lds[k * 33 + c + 3] = v.w;
    }
    __syncthreads();
    #pragma unroll
    for (int i = 0; i < 4; ++i) {
        int g  = tid + i * 256;
        int nl = g >> 5;
        int k4 = (g & 31) * 4;
        int n  = n0 + nl;
        int nt  = n >> 4, n16 = n & 15;
        int kk  = k4 >> 5, q = (k4 >> 3) & 3, jb = k4 & 7;
        int lane = q * 16 + n16;
        size_t ofs = ((((size_t)t * 8 + nt) * 4 + kk) * 64 + lane) * 8 + jb;
        ushort4 o;
        union { __bf16 b; unsigned short u; } cv;
        cv.b = (__bf16)lds[(k4 + 0) * 33 + nl]; o.x = cv.u;
        cv.b = (__bf16)lds[(k4 + 1) * 33 + nl]; o.y = cv.u;
        cv.b = (__bf16)lds[(k4 + 2) * 33 + nl]; o.z = cv.u;
        cv.b = (__bf16)lds[(k4 + 3) * 33 + nl]; o.w = cv.u;
        *(ushort4*)&wbf[ofs] = o;
    }
}

// ---------- Main kernel ----------
// A-fragments loaded DIRECTLY from global in MFMA layout (no LDS round-trip).
// LDS = Bs only (32 KB). launch_bounds(256,4) -> 4 blocks/CU -> the whole
// 1024-block grid is co-resident; cross-block TLP hides all memory latency.
__global__ __launch_bounds__(256, 4) void hetero_main_kernel(
    const float* __restrict__ x,
    const int*   __restrict__ tv,
    const __bf16* __restrict__ wbf,   // fragment-ordered bf16 W
    const float* __restrict__ bias,   // [T][128]
    float*       __restrict__ out)    // [N][128]
{
    __shared__ __bf16 Bs[DD * DD];       // 32 KB, fragment order

    const int tid  = threadIdx.x;
    const int wave = tid >> 6;
    const int lane = tid & 63;
    const int q    = lane >> 4;
    const int n16  = lane & 15;
    const int chunk0 = blockIdx.x * (BM * CHUNK);

    int t_res = tv[chunk0];

    // ---- W[t_res] -> Bs: 8 async DMA insts/wave, zero VGPR cost ----
    {
        const char* gsrc = (const char*)(wbf + (size_t)t_res * DD * DD);
        char* ldst = (char*)Bs;
        const int wofs = wave * 1024 + lane * 16;
        #pragma unroll
        for (int r = 0; r < 8; ++r)
            async_copy16(gsrc + r * 4096 + wofs, ldst + r * 4096 + wave * 1024);
    }

    // bias cached in regs for resident type
    float bv[8];
    #pragma unroll
    for (int nt = 0; nt < 8; ++nt) bv[nt] = bias[t_res * DD + nt * 16 + n16];

    // ---- prefetch x tile 0 directly in fragment order ----
    f32x4 xlo[4], xhi[4];
    {
        const float* base = x + (size_t)(chunk0 + wave * 16 + n16) * DD + q * 8;
        #pragma unroll
        for (int kk = 0; kk < 4; ++kk) {
            xlo[kk] = *(const f32x4*)(base + kk * 32);
            xhi[kk] = *(const f32x4*)(base + kk * 32 + 4);
        }
    }

    __syncthreads();   // drain W DMA (all waves read all of Bs)

    #pragma unroll
    for (int tile = 0; tile < CHUNK; ++tile) {
        const int trow0 = chunk0 + tile * BM;
        const int wrow0 = trow0 + wave * 16;

        // issue next tile's prefetch first -> loads fly under this tile's compute
        f32x4 nlo[4], nhi[4];
        if (tile + 1 < CHUNK) {
            const float* base = x + (size_t)(wrow0 + BM + n16) * DD + q * 8;
            #pragma unroll
            for (int kk = 0; kk < 4; ++kk) {
                nlo[kk] = *(const f32x4*)(base + kk * 32);
                nhi[kk] = *(const f32x4*)(base + kk * 32 + 4);
            }
        }

        // pack A fragments: A[m=n16][k=kk*32+q*8+j]
        bf16x8 a[4];
        #pragma unroll
        for (int kk = 0; kk < 4; ++kk) {
            bf16x8 t;
            t[0] = (__bf16)xlo[kk][0]; t[1] = (__bf16)xlo[kk][1];
            t[2] = (__bf16)xlo[kk][2]; t[3] = (__bf16)xlo[kk][3];
            t[4] = (__bf16)xhi[kk][0]; t[5] = (__bf16)xhi[kk][1];
            t[6] = (__bf16)xhi[kk][2]; t[7] = (__bf16)xhi[kk][3];
            a[kk] = t;
        }

        const int tlo = tv[trow0];
        const int thi = tv[trow0 + BM - 1];

        for (int t = tlo; t <= thi; ++t) {
            if (t != t_res) {               // rare: block-uniform branch
                __syncthreads();            // all waves done reading old Bs
                const char* gsrc = (const char*)(wbf + (size_t)t * DD * DD);
                char* ldst = (char*)Bs;
                const int wofs = wave * 1024 + lane * 16;
                #pragma unroll
                for (int r = 0; r < 8; ++r)
                    async_copy16(gsrc + r * 4096 + wofs, ldst + r * 4096 + wave * 1024);
                t_res = t;
                #pragma unroll
                for (int nt = 0; nt < 8; ++nt) bv[nt] = bias[t * DD + nt * 16 + n16];
                __syncthreads();
            }

            f32x4 acc[8];
            #pragma unroll
            for (int nt = 0; nt < 8; ++nt) acc[nt] = (f32x4){0.f, 0.f, 0.f, 0.f};

            #pragma unroll
            for (int nt = 0; nt < 8; ++nt) {
                #pragma unroll
                for (int kk = 0; kk < 4; ++kk) {
                    bf16x8 b = *(const bf16x8*)&Bs[(((nt << 2) | kk) << 9) | (lane << 3)];
                    acc[nt] = __builtin_amdgcn_mfma_f32_16x16x32_bf16(a[kk], b, acc[nt], 0, 0, 0);
                }
            }

            // epilogue: D[row=q*4+reg][col=nt*16+n16]; 4x64B segments per store,
            // adjacent nt pairs merge into full 128B lines in L2.
            const int rbase = wrow0 + q * 4;
            bool m0 = true, m1 = true, m2 = true, m3 = true;
            if (tlo != thi) {
                m0 = (tv[rbase + 0] == t);
                m1 = (tv[rbase + 1] == t);
                m2 = (tv[rbase + 2] == t);
                m3 = (tv[rbase + 3] == t);
            }
            float* o = out + (size_t)rbase * DD + n16;
            #pragma unroll
            for (int nt = 0; nt < 8; ++nt) {
                float* oc = o + nt * 16;
                if (m0) oc[0 * DD] = acc[nt][0] + bv[nt];
                if (m1) oc[1 * DD] = acc[nt][1] + bv[nt];
                if (m2) oc[2 * DD] = acc[nt][2] + bv[nt];
                if (m3) oc[3 * DD] = acc[nt][3] + bv[nt];
            }
        }

        // hand prefetch buffer over
        #pragma unroll
        for (int kk = 0; kk < 4; ++kk) { xlo[kk] = nlo[kk]; xhi[kk] = nhi[kk]; }
    }
}

extern "C" void kernel_launch(void* const* d_in, const int* in_sizes, int n_in,
                              void* d_out, int out_size, void* d_ws, size_t ws_size,
                              hipStream_t stream) {
    const float* x    = (const float*)d_in[0];
    const int*   tv   = (const int*)d_in[1];
    const float* w    = (const float*)d_in[2];
    const float* bias = (const float*)d_in[3];
    float*       out  = (float*)d_out;
    unsigned short* wbf = (unsigned short*)d_ws;   // 512 KB

    int nrows = in_sizes[0] / DD;                  // 131072
    int grid  = nrows / (BM * CHUNK);              // 1024

    hipLaunchKernelGGL(transpose_w_frag_kernel, dim3(T_TYPES * 4), dim3(256), 0, stream,
                       w, wbf);
    hipLaunchKernelGGL(hetero_main_kernel, dim3(grid), dim3(256), 0, stream,
                       x, tv, (const __bf16*)wbf, bias, out);
}